// Round 1
// baseline (74.437 us; speedup 1.0000x reference)
//
#include <hip/hip_runtime.h>

#define SCALE 64.0f
#define MARGIN 0.5f

constexpr int BLOCK = 256;
constexpr int GRID = 2048;

__device__ __forceinline__ float sample_loss(float d0, float d1, int lab) {
    // pos = dist[label], neg = dist[1-label]
    float pos = lab ? d1 : d0;
    float neg = lab ? d0 : d1;
    float lp = SCALE * cosf(pos + MARGIN);
    float ln = SCALE * cosf(neg);
    float d  = ln - lp;
    // logaddexp(lp, ln) - lp = softplus(d), stable form
    return fmaxf(d, 0.0f) + log1pf(expf(-fabsf(d)));
}

__device__ __forceinline__ float block_reduce(float acc) {
    // wave-64 butterfly-free down-reduce
    #pragma unroll
    for (int off = 32; off > 0; off >>= 1)
        acc += __shfl_down(acc, off, 64);
    __shared__ float warp_sums[BLOCK / 64];
    int wave = threadIdx.x >> 6;
    int lane = threadIdx.x & 63;
    if (lane == 0) warp_sums[wave] = acc;
    __syncthreads();
    if (threadIdx.x == 0) {
        float s = warp_sums[0];
        #pragma unroll
        for (int w = 1; w < BLOCK / 64; ++w) s += warp_sums[w];
        return s;
    }
    return 0.0f;
}

__global__ __launch_bounds__(BLOCK) void loss_partial_kernel(
    const float* __restrict__ dist, const int* __restrict__ label,
    float* __restrict__ partial, int n)
{
    const int nvec = n >> 2;  // n divisible by 4 (N = 2^24)
    const float4* __restrict__ row0 = reinterpret_cast<const float4*>(dist);
    const float4* __restrict__ row1 = reinterpret_cast<const float4*>(dist + n);
    const int4*   __restrict__ lab4 = reinterpret_cast<const int4*>(label);

    float acc = 0.0f;
    for (int i = blockIdx.x * BLOCK + threadIdx.x; i < nvec; i += gridDim.x * BLOCK) {
        float4 a = row0[i];
        float4 b = row1[i];
        int4   l = lab4[i];
        acc += sample_loss(a.x, b.x, l.x);
        acc += sample_loss(a.y, b.y, l.y);
        acc += sample_loss(a.z, b.z, l.z);
        acc += sample_loss(a.w, b.w, l.w);
    }

    float s = block_reduce(acc);
    if (threadIdx.x == 0) partial[blockIdx.x] = s;
}

__global__ __launch_bounds__(BLOCK) void reduce_partials_kernel(
    const float* __restrict__ partial, float* __restrict__ out, int nparts)
{
    float acc = 0.0f;
    for (int i = threadIdx.x; i < nparts; i += BLOCK) acc += partial[i];
    float s = block_reduce(acc);
    if (threadIdx.x == 0) out[0] = s;
}

extern "C" void kernel_launch(void* const* d_in, const int* in_sizes, int n_in,
                              void* d_out, int out_size, void* d_ws, size_t ws_size,
                              hipStream_t stream) {
    const float* dist  = (const float*)d_in[0];
    const int*   label = (const int*)d_in[1];
    float* out = (float*)d_out;
    float* partial = (float*)d_ws;

    const int n = in_sizes[0] / 2;  // N samples (dist is 2 x N)

    loss_partial_kernel<<<GRID, BLOCK, 0, stream>>>(dist, label, partial, n);
    reduce_partials_kernel<<<1, BLOCK, 0, stream>>>(partial, out, GRID);
}

// Round 2
// 40.029 us; speedup vs baseline: 1.8596x; 1.8596x over previous
//
#include <hip/hip_runtime.h>

#define SCALE 64.0f
#define MARGIN 0.5f

constexpr int BLOCK = 256;
constexpr int GRID = 2048;

// cos(x) for x in radians via the HW TRANS pipe (v_cos_f32 takes revolutions).
// Explicit fract keeps the argument in [0,1) for any input (cos has period 1 rev).
__device__ __forceinline__ float cos_fast(float x) {
    float r = x * 0.15915494309189535f;   // radians -> revolutions
    r = r - floorf(r);                    // folds to v_fract_f32
    return __builtin_amdgcn_cosf(r);      // v_cos_f32
}

__device__ __forceinline__ float sample_loss(float d0, float d1, int lab) {
    // pos = dist[label], neg = dist[1-label]
    float pos = lab ? d1 : d0;
    float neg = lab ? d0 : d1;
    float c1 = cos_fast(pos + MARGIN);    // cos(pos + m)
    float c0 = cos_fast(neg);             // cos(neg)
    float d  = (c0 - c1) * SCALE;         // ln - lp
    // logaddexp(lp, ln) - lp = softplus(d), stable form; fast intrinsics
    float t  = __expf(-fabsf(d));         // v_exp_f32 (+1 mul)
    float s  = __logf(1.0f + t);          // v_log_f32 (+1 mul)
    return fmaxf(d, 0.0f) + s;
}

__device__ __forceinline__ float block_reduce(float acc) {
    #pragma unroll
    for (int off = 32; off > 0; off >>= 1)
        acc += __shfl_down(acc, off, 64);
    __shared__ float warp_sums[BLOCK / 64];
    int wave = threadIdx.x >> 6;
    int lane = threadIdx.x & 63;
    if (lane == 0) warp_sums[wave] = acc;
    __syncthreads();
    if (threadIdx.x == 0) {
        float s = warp_sums[0];
        #pragma unroll
        for (int w = 1; w < BLOCK / 64; ++w) s += warp_sums[w];
        return s;
    }
    return 0.0f;
}

__global__ __launch_bounds__(BLOCK) void loss_partial_kernel(
    const float* __restrict__ dist, const int* __restrict__ label,
    float* __restrict__ partial, int n)
{
    const int nvec = n >> 2;  // N = 2^24, divisible by 4
    const float4* __restrict__ row0 = reinterpret_cast<const float4*>(dist);
    const float4* __restrict__ row1 = reinterpret_cast<const float4*>(dist + n);
    const int4*   __restrict__ lab4 = reinterpret_cast<const int4*>(label);

    float acc = 0.0f;
    for (int i = blockIdx.x * BLOCK + threadIdx.x; i < nvec; i += gridDim.x * BLOCK) {
        float4 a = row0[i];
        float4 b = row1[i];
        int4   l = lab4[i];
        acc += sample_loss(a.x, b.x, l.x);
        acc += sample_loss(a.y, b.y, l.y);
        acc += sample_loss(a.z, b.z, l.z);
        acc += sample_loss(a.w, b.w, l.w);
    }

    float s = block_reduce(acc);
    if (threadIdx.x == 0) partial[blockIdx.x] = s;
}

__global__ __launch_bounds__(BLOCK) void reduce_partials_kernel(
    const float* __restrict__ partial, float* __restrict__ out, int nparts)
{
    float acc = 0.0f;
    for (int i = threadIdx.x; i < nparts; i += BLOCK) acc += partial[i];
    float s = block_reduce(acc);
    if (threadIdx.x == 0) out[0] = s;
}

extern "C" void kernel_launch(void* const* d_in, const int* in_sizes, int n_in,
                              void* d_out, int out_size, void* d_ws, size_t ws_size,
                              hipStream_t stream) {
    const float* dist  = (const float*)d_in[0];
    const int*   label = (const int*)d_in[1];
    float* out = (float*)d_out;
    float* partial = (float*)d_ws;

    const int n = in_sizes[0] / 2;  // N samples (dist is 2 x N)

    loss_partial_kernel<<<GRID, BLOCK, 0, stream>>>(dist, label, partial, n);
    reduce_partials_kernel<<<1, BLOCK, 0, stream>>>(partial, out, GRID);
}